// Round 6
// baseline (383.830 us; speedup 1.0000x reference)
//
#include <hip/hip_runtime.h>
#include <math.h>

#define NN 4096
#define KTILES 64

typedef __bf16 bf16;
typedef __attribute__((ext_vector_type(4))) __bf16 bf16x4;
typedef __attribute__((ext_vector_type(8))) __bf16 bf16x8;
typedef __attribute__((ext_vector_type(4))) float f32x4;

#define MFMA16(a, b, c) __builtin_amdgcn_mfma_f32_16x16x32_bf16((a), (b), (c), 0, 0, 0)

__device__ __forceinline__ void gld16(const void* g, void* l) {
  __builtin_amdgcn_global_load_lds((const __attribute__((address_space(1))) void*)g,
                                   (__attribute__((address_space(3))) void*)l, 16, 0, 0);
}

// ---------- block reduction helpers (blockDim.x == 256) ----------

__device__ __forceinline__ double blockSumD(double v) {
  __shared__ double w[4];
  #pragma unroll
  for (int o = 32; o > 0; o >>= 1) v += __shfl_down(v, o, 64);
  __syncthreads();
  if ((threadIdx.x & 63) == 0) w[threadIdx.x >> 6] = v;
  __syncthreads();
  return w[0] + w[1] + w[2] + w[3];
}

__device__ __forceinline__ float blockMaxF(float v) {
  __shared__ float w[4];
  #pragma unroll
  for (int o = 32; o > 0; o >>= 1) v = fmaxf(v, __shfl_down(v, o, 64));
  __syncthreads();
  if ((threadIdx.x & 63) == 0) w[threadIdx.x >> 6] = v;
  __syncthreads();
  return fmaxf(fmaxf(w[0], w[1]), fmaxf(w[2], w[3]));
}

// ---------- kernel 1: row softmax of x,y -> bf16 (vectorized), exact row sum-of-squares ----------

__global__ void softmax_rows(const float* __restrict__ x, const float* __restrict__ y,
                             bf16* __restrict__ xh, bf16* __restrict__ yh,
                             float* __restrict__ rowsq) {
  int row = blockIdx.x;
  int r = (row < NN) ? row : row - NN;
  const f32x4* __restrict__ src = (const f32x4*)(((row < NN) ? x : y) + (size_t)r * NN);
  bf16x4* __restrict__ dst = (bf16x4*)(((row < NN) ? xh : yh) + (size_t)r * NN);
  int t = threadIdx.x;

  f32x4 v[4];
  float m = -3.402823466e38f;
  #pragma unroll
  for (int j = 0; j < 4; ++j) {
    v[j] = src[t + 256 * j];
    m = fmaxf(fmaxf(fmaxf(m, v[j].x), fmaxf(v[j].y, v[j].z)), v[j].w);
  }
  float M = blockMaxF(m);

  float s = 0.0f;
  #pragma unroll
  for (int j = 0; j < 4; ++j) {
    v[j].x = expf(v[j].x - M); v[j].y = expf(v[j].y - M);
    v[j].z = expf(v[j].z - M); v[j].w = expf(v[j].w - M);
    s += (v[j].x + v[j].y) + (v[j].z + v[j].w);
  }
  double S = blockSumD((double)s);
  float inv = (float)(1.0 / S);

  float q = 0.0f;
  #pragma unroll
  for (int j = 0; j < 4; ++j) {
    f32x4 p = v[j] * inv;
    bf16x4 h;
    h.x = (bf16)p.x; h.y = (bf16)p.y; h.z = (bf16)p.z; h.w = (bf16)p.w;
    dst[t + 256 * j] = h;
    q += (p.x * p.x + p.y * p.y) + (p.z * p.z + p.w * p.w);
  }
  double Q = blockSumD((double)q);
  if (t == 0) rowsq[row] = (float)Q;
}

// ---------- kernel 2: C = x2 + y2 - 2 * sx . sy^T (bf16 MFMA) + fused column exp-sums ----------
// 256x256 tile, BK=64, 8 waves (2Mx4N), 128 KiB double-buffered LDS.
// Cross-phase read pipelining: each phase's ds_reads are issued at the
// TOP of the PREVIOUS phase, so their LDS service overlaps the previous MFMA burst;
// drains are counted-lgkm (leave the just-issued reads in flight):
//   ph1: issue bhi(4);  drain lgkm(4)  -> alo+blo (issued ph4 of prev tile)
//   ph2: issue ahi(8);  drain lgkm(8)  -> bhi
//   ph3: (no reads);    drain lgkm(0)  -> ahi
//   ph4: issue next alo+blo(12) AFTER vmcnt(6)+barrier, BEFORE MFMA; no drain needed
// Staging: ph1 -> (tt+1).A1 (other buffer); ph3 -> (tt+2).B0+B1 (B readers formally
// drained at ph2's lgkm(8) + barrier); ph4 -> (tt+2).A0 (A readers drained ph3).
// vmcnt(6) at ph4 leaves the 3 youngest half-tiles in flight; barrier after it
// guarantees tile tt+1 fully staged before the read-ahead touches it.

__global__ __launch_bounds__(512, 2) void gemm_bt(const bf16* __restrict__ A,
                                                  const bf16* __restrict__ B,
                                                  const float* __restrict__ rowsq,
                                                  float* __restrict__ C,
                                                  float* __restrict__ colpart) {
  __shared__ __align__(16) bf16 sm[2][4][8192];
  __shared__ float lsc[2][256];
  char* smb = (char*)sm;

  const int t = threadIdx.x;
  const int i0 = blockIdx.y * 256;
  const int j0 = blockIdx.x * 256;
  const int w = t >> 6, l = t & 63;
  const int wr = w >> 2, wc = w & 3;      // wave grid 2 (M) x 4 (N)
  const int lr = l & 15, lq = l >> 4;

  // staging constants: 2 x 16B chunks per thread per half-tile (128x64 bf16 = 1024 chunks)
  const int c0 = t, c1 = t + 512;
  const int r0 = c0 >> 3, r1 = c1 >> 3;
  const int g0 = ((c0 & 7) ^ (r0 & 7)) * 8;   // pre-swizzled source column (bf16 units)
  const int g1 = ((c1 & 7) ^ (r1 & 7)) * 8;

  const bf16* A0p = A + (size_t)i0 * NN;            // A rows i0 +   0..127
  const bf16* A1p = A0p + (size_t)128 * NN;         // A rows i0 + 128..255
  const bf16* B0p = B + (size_t)j0 * NN;
  const bf16* B1p = B0p + (size_t)128 * NN;

  // ds_read constants
  const int jx0 = lq ^ (lr & 7);
  const int jx1 = (4 + lq) ^ (lr & 7);
  const int aO0 = lr * 128 + jx0 * 16;
  const int aO1 = lr * 128 + jx1 * 16;
  const int brO = (wc & 1) * 8192;                  // 64-row offset within B half

  f32x4 acc[8][4] = {};
  bf16x8 alo[4][2], ahi[4][2], blo[2][2], bhi[2][2];

  auto STG = [&](const bf16* gp, char* ld) {
    gld16(gp + (size_t)r0 * NN + g0, ld + c0 * 16);
    gld16(gp + (size_t)r1 * NN + g1, ld + c1 * 16);
  };

  // ---- prologue: stage 0.B0 0.B1 0.A0 0.A1 1.B0 1.B1 1.A0 (7 half-tiles = 14 loads) ----
  {
    char* s0 = smb;
    char* s1 = smb + 65536;
    STG(B0p, s0 + 32768);
    STG(B1p, s0 + 49152);
    STG(A0p, s0);
    STG(A1p, s0 + 16384);
    STG(B0p + 64, s1 + 32768);
    STG(B1p + 64, s1 + 49152);
    STG(A0p + 64, s1);
  }
  asm volatile("s_waitcnt vmcnt(6)" ::: "memory");   // K-tile 0 fully staged
  __builtin_amdgcn_s_barrier();
  {
    const char* Arw = smb + wr * 16384;
    const char* Brw = smb + 32768 + ((wc >> 1) << 14) + brO;
    #pragma unroll
    for (int i = 0; i < 4; ++i) {
      alo[i][0] = *(const bf16x8*)(Arw + i * 2048 + aO0);
      alo[i][1] = *(const bf16x8*)(Arw + i * 2048 + aO1);
    }
    #pragma unroll
    for (int jj = 0; jj < 2; ++jj) {
      blo[jj][0] = *(const bf16x8*)(Brw + jj * 2048 + aO0);
      blo[jj][1] = *(const bf16x8*)(Brw + jj * 2048 + aO1);
    }
  }

  #pragma unroll 1
  for (int tt = 0; tt < KTILES; ++tt) {
    const int cur = tt & 1;
    char* baseC = smb + (cur << 16);
    char* baseN = smb + ((cur ^ 1) << 16);
    const char* Arw = baseC + wr * 16384;
    const char* Brw = baseC + 32768 + ((wc >> 1) << 14) + brO;
    const char* ArwN = baseN + wr * 16384;
    const char* BrwN = baseN + 32768 + ((wc >> 1) << 14) + brO;

    // ---- phase 1: issue bhi; STG (tt+1).A1; drain alo/blo; MFMA Alo x Blo ----
    #pragma unroll
    for (int jj = 0; jj < 2; ++jj) {
      bhi[jj][0] = *(const bf16x8*)(Brw + (2 + jj) * 2048 + aO0);
      bhi[jj][1] = *(const bf16x8*)(Brw + (2 + jj) * 2048 + aO1);
    }
    if (tt < KTILES - 1) STG(A1p + (tt + 1) * 64, baseN + 16384);
    __builtin_amdgcn_sched_barrier(0);
    __builtin_amdgcn_s_barrier();
    asm volatile("s_waitcnt lgkmcnt(4)" ::: "memory");  // drain alo+blo, leave bhi in flight
    __builtin_amdgcn_sched_barrier(0);
    __builtin_amdgcn_s_setprio(1);
    #pragma unroll
    for (int i = 0; i < 4; ++i)
      #pragma unroll
      for (int jj = 0; jj < 2; ++jj) {
        acc[i][jj] = MFMA16(alo[i][0], blo[jj][0], acc[i][jj]);
        acc[i][jj] = MFMA16(alo[i][1], blo[jj][1], acc[i][jj]);
      }
    __builtin_amdgcn_s_setprio(0);
    __builtin_amdgcn_s_barrier();

    // ---- phase 2: issue ahi; drain bhi (counted); MFMA Alo x Bhi ----
    #pragma unroll
    for (int i = 0; i < 4; ++i) {
      ahi[i][0] = *(const bf16x8*)(Arw + 8192 + i * 2048 + aO0);
      ahi[i][1] = *(const bf16x8*)(Arw + 8192 + i * 2048 + aO1);
    }
    __builtin_amdgcn_sched_barrier(0);
    __builtin_amdgcn_s_barrier();
    asm volatile("s_waitcnt lgkmcnt(8)" ::: "memory");  // drain bhi, leave ahi in flight
    __builtin_amdgcn_sched_barrier(0);
    __builtin_amdgcn_s_setprio(1);
    #pragma unroll
    for (int i = 0; i < 4; ++i)
      #pragma unroll
      for (int jj = 0; jj < 2; ++jj) {
        acc[i][2 + jj] = MFMA16(alo[i][0], bhi[jj][0], acc[i][2 + jj]);
        acc[i][2 + jj] = MFMA16(alo[i][1], bhi[jj][1], acc[i][2 + jj]);
      }
    __builtin_amdgcn_s_setprio(0);
    __builtin_amdgcn_s_barrier();

    // ---- phase 3: STG (tt+2).B0+B1 (B readers drained ph2+barrier); drain ahi; MFMA Ahi x Blo ----
    if (tt < KTILES - 2) {
      STG(B0p + (tt + 2) * 64, baseC + 32768);
      STG(B1p + (tt + 2) * 64, baseC + 49152);
    }
    __builtin_amdgcn_sched_barrier(0);
    __builtin_amdgcn_s_barrier();
    asm volatile("s_waitcnt lgkmcnt(0)" ::: "memory");  // drain ahi (serviced under ph2 MFMA)
    __builtin_amdgcn_sched_barrier(0);
    __builtin_amdgcn_s_setprio(1);
    #pragma unroll
    for (int i = 0; i < 4; ++i)
      #pragma unroll
      for (int jj = 0; jj < 2; ++jj) {
        acc[4 + i][jj] = MFMA16(ahi[i][0], blo[jj][0], acc[4 + i][jj]);
        acc[4 + i][jj] = MFMA16(ahi[i][1], blo[jj][1], acc[4 + i][jj]);
      }
    __builtin_amdgcn_s_setprio(0);
    __builtin_amdgcn_s_barrier();

    // ---- phase 4: STG (tt+2).A0; counted vmcnt; barrier; read-ahead next alo+blo;
    //      MFMA Ahi x Bhi (operands already resident - no lgkm drain) ----
    if (tt < KTILES - 2) {
      STG(A0p + (tt + 2) * 64, baseC);
      asm volatile("s_waitcnt vmcnt(6)" ::: "memory");   // tile tt+1 fully staged
    } else if (tt == KTILES - 2) {
      asm volatile("s_waitcnt vmcnt(0)" ::: "memory");   // drain for the final K-tile
    }
    __builtin_amdgcn_s_barrier();
    if (tt < KTILES - 1) {
      #pragma unroll
      for (int i = 0; i < 4; ++i) {
        alo[i][0] = *(const bf16x8*)(ArwN + i * 2048 + aO0);
        alo[i][1] = *(const bf16x8*)(ArwN + i * 2048 + aO1);
      }
      #pragma unroll
      for (int jj = 0; jj < 2; ++jj) {
        blo[jj][0] = *(const bf16x8*)(BrwN + jj * 2048 + aO0);
        blo[jj][1] = *(const bf16x8*)(BrwN + jj * 2048 + aO1);
      }
    }
    __builtin_amdgcn_sched_barrier(0);
    __builtin_amdgcn_s_setprio(1);
    #pragma unroll
    for (int i = 0; i < 4; ++i)
      #pragma unroll
      for (int jj = 0; jj < 2; ++jj) {
        acc[4 + i][2 + jj] = MFMA16(ahi[i][0], bhi[jj][0], acc[4 + i][2 + jj]);
        acc[4 + i][2 + jj] = MFMA16(ahi[i][1], bhi[jj][1], acc[4 + i][2 + jj]);
      }
    __builtin_amdgcn_s_setprio(0);
    __builtin_amdgcn_s_barrier();
  }

  // ---- epilogue: C = x2 + y2 - 2*acc, fused colpart = sum_rows exp(-10*C) ----
  float y2v[4], ec[4] = {0.f, 0.f, 0.f, 0.f};
  #pragma unroll
  for (int jj = 0; jj < 4; ++jj) y2v[jj] = rowsq[NN + j0 + wc * 64 + 16 * jj + lr];
  #pragma unroll
  for (int m = 0; m < 8; ++m) {
    #pragma unroll
    for (int r = 0; r < 4; ++r) {
      int grow = i0 + wr * 128 + 16 * m + lq * 4 + r;
      float x2 = rowsq[grow];
      size_t rowoff = (size_t)grow * NN + j0 + wc * 64;
      #pragma unroll
      for (int jj = 0; jj < 4; ++jj) {
        float cv = x2 + y2v[jj] - 2.0f * acc[m][jj][r];
        C[rowoff + 16 * jj + lr] = cv;
        ec[jj] += expf(-10.0f * cv);
      }
    }
  }
  // reduce over lq (lanes lr, lr+16, lr+32, lr+48 hold the same columns)
  #pragma unroll
  for (int jj = 0; jj < 4; ++jj) {
    ec[jj] += __shfl_xor(ec[jj], 16, 64);
    ec[jj] += __shfl_xor(ec[jj], 32, 64);
  }
  if (lq == 0) {
    #pragma unroll
    for (int jj = 0; jj < 4; ++jj) lsc[wr][wc * 64 + 16 * jj + lr] = ec[jj];
  }
  __syncthreads();
  if (t < 256) colpart[(size_t)blockIdx.y * NN + j0 + t] = lsc[0][t] + lsc[1][t];
}

// ---------- kernel 3: s_j = log_nu - log(colsum) as fp32 ----------

__global__ void col_lse_final(const float* __restrict__ colpart, float* __restrict__ sdf) {
  int col = blockIdx.x * 256 + threadIdx.x;
  double s = 0.0;
  #pragma unroll
  for (int ch = 0; ch < 16; ++ch) s += (double)colpart[(size_t)ch * NN + col];
  double log_nu = log(1.0 / (double)NN + 1e-8);
  sdf[col] = (float)(log_nu - log(s));
}

// ---------- kernel 4: pi = exp(-10*C + s_j), fused cost partials (fp32 math) ----------

__global__ void pi_cost(const float* __restrict__ Cm, const float* __restrict__ sdf,
                        float* __restrict__ pi, double* __restrict__ costpart) {
  size_t idx0 = (size_t)blockIdx.x * 2048 + threadIdx.x;
  float facc = 0.0f;
  #pragma unroll
  for (int j = 0; j < 8; ++j) {
    size_t idx = idx0 + 256 * j;
    float c = Cm[idx];
    int col = (int)(idx & (NN - 1));
    float p = expf(fmaf(-10.0f, c, sdf[col]));
    pi[idx] = p;
    facc = fmaf(p, c, facc);
  }
  double total = blockSumD((double)facc);
  if (threadIdx.x == 0) costpart[blockIdx.x] = total;
}

// ---------- kernel 5: final cost reduction ----------

__global__ void cost_final(const double* __restrict__ costpart, float* __restrict__ out) {
  double s = 0.0;
  #pragma unroll
  for (int j = 0; j < 32; ++j) s += costpart[threadIdx.x + 256 * j];
  double total = blockSumD(s);
  if (threadIdx.x == 0) out[0] = (float)total;
}

// ---------- launch ----------

extern "C" void kernel_launch(void* const* d_in, const int* in_sizes, int n_in,
                              void* d_out, int out_size, void* d_ws, size_t ws_size,
                              hipStream_t stream) {
  const float* x = (const float*)d_in[0];
  const float* y = (const float*)d_in[1];
  float* out = (float*)d_out;
  float* pi = out + 1;                          // [NN*NN] floats
  float* Cm = out + 1 + (size_t)NN * NN;        // [NN*NN] floats

  char* ws = (char*)d_ws;
  bf16* xh = (bf16*)ws;                                          // 32 MiB
  bf16* yh = xh + (size_t)NN * NN;                               // 32 MiB
  size_t off = (size_t)NN * NN * 2 * 2;
  float* rowsq = (float*)(ws + off);       off += 2 * NN * 4;    // 32 KiB
  float* sdf = (float*)(ws + off);         off += NN * 4;        // 16 KiB
  float* colpart = (float*)(ws + off);     off += 32 * NN * 4;   // 512 KiB (16 rows used)
  double* costpart = (double*)(ws + off);  off += 8192 * 8;      // 64 KiB

  hipLaunchKernelGGL(softmax_rows, dim3(2 * NN), dim3(256), 0, stream, x, y, xh, yh, rowsq);
  hipLaunchKernelGGL(gemm_bt, dim3(16, 16), dim3(512), 0, stream, xh, yh, rowsq, Cm, colpart);
  hipLaunchKernelGGL(col_lse_final, dim3(16), dim3(256), 0, stream, colpart, sdf);
  hipLaunchKernelGGL(pi_cost, dim3(8192), dim3(256), 0, stream, Cm, sdf, pi, costpart);
  hipLaunchKernelGGL(cost_final, dim3(1), dim3(256), 0, stream, costpart, out);
}

// Round 7
// 366.251 us; speedup vs baseline: 1.0480x; 1.0480x over previous
//
#include <hip/hip_runtime.h>
#include <math.h>

#define NN 4096
#define KTILES 64

typedef __bf16 bf16;
typedef __attribute__((ext_vector_type(4))) __bf16 bf16x4;
typedef __attribute__((ext_vector_type(8))) __bf16 bf16x8;
typedef __attribute__((ext_vector_type(4))) float f32x4;

#define MFMA16(a, b, c) __builtin_amdgcn_mfma_f32_16x16x32_bf16((a), (b), (c), 0, 0, 0)

__device__ __forceinline__ void gld16(const void* g, void* l) {
  __builtin_amdgcn_global_load_lds((const __attribute__((address_space(1))) void*)g,
                                   (__attribute__((address_space(3))) void*)l, 16, 0, 0);
}

// ---------- block reduction helpers (blockDim.x == 256) ----------

__device__ __forceinline__ double blockSumD(double v) {
  __shared__ double w[4];
  #pragma unroll
  for (int o = 32; o > 0; o >>= 1) v += __shfl_down(v, o, 64);
  __syncthreads();
  if ((threadIdx.x & 63) == 0) w[threadIdx.x >> 6] = v;
  __syncthreads();
  return w[0] + w[1] + w[2] + w[3];
}

__device__ __forceinline__ float blockMaxF(float v) {
  __shared__ float w[4];
  #pragma unroll
  for (int o = 32; o > 0; o >>= 1) v = fmaxf(v, __shfl_down(v, o, 64));
  __syncthreads();
  if ((threadIdx.x & 63) == 0) w[threadIdx.x >> 6] = v;
  __syncthreads();
  return fmaxf(fmaxf(w[0], w[1]), fmaxf(w[2], w[3]));
}

// ---------- kernel 1: row softmax of x,y -> bf16 (vectorized), exact row sum-of-squares ----------

__global__ void softmax_rows(const float* __restrict__ x, const float* __restrict__ y,
                             bf16* __restrict__ xh, bf16* __restrict__ yh,
                             float* __restrict__ rowsq) {
  int row = blockIdx.x;
  int r = (row < NN) ? row : row - NN;
  const f32x4* __restrict__ src = (const f32x4*)(((row < NN) ? x : y) + (size_t)r * NN);
  bf16x4* __restrict__ dst = (bf16x4*)(((row < NN) ? xh : yh) + (size_t)r * NN);
  int t = threadIdx.x;

  f32x4 v[4];
  float m = -3.402823466e38f;
  #pragma unroll
  for (int j = 0; j < 4; ++j) {
    v[j] = src[t + 256 * j];
    m = fmaxf(fmaxf(fmaxf(m, v[j].x), fmaxf(v[j].y, v[j].z)), v[j].w);
  }
  float M = blockMaxF(m);

  float s = 0.0f;
  #pragma unroll
  for (int j = 0; j < 4; ++j) {
    v[j].x = expf(v[j].x - M); v[j].y = expf(v[j].y - M);
    v[j].z = expf(v[j].z - M); v[j].w = expf(v[j].w - M);
    s += (v[j].x + v[j].y) + (v[j].z + v[j].w);
  }
  double S = blockSumD((double)s);
  float inv = (float)(1.0 / S);

  float q = 0.0f;
  #pragma unroll
  for (int j = 0; j < 4; ++j) {
    f32x4 p = v[j] * inv;
    bf16x4 h;
    h.x = (bf16)p.x; h.y = (bf16)p.y; h.z = (bf16)p.z; h.w = (bf16)p.w;
    dst[t + 256 * j] = h;
    q += (p.x * p.x + p.y * p.y) + (p.z * p.z + p.w * p.w);
  }
  double Q = blockSumD((double)q);
  if (t == 0) rowsq[row] = (float)Q;
}

// ---------- kernel 2: C = x2 + y2 - 2 * sx . sy^T (bf16 MFMA) + fused column exp-sums ----------
// 256x256 tile, BK=64, 8 waves (2Mx4N), 128 KiB double-buffered LDS.
// v0 structure (best measured: 140us / MfmaUtil 43) + m201 read distribution:
// every phase reads ITS OWN operands just before its barrier (same-phase pattern),
// bursts evened to 12,4,8,0 reads/phase (was 16,0,8,0):
//   ph1: read blo(4)+alo(8); STG (tt+1).A1; lgkm(8) smooth; bar; lgkm(0); MFMA alo x blo
//   ph2: read bhi(4);        STG (tt+2).B0;                 bar; lgkm(0); MFMA alo x bhi
//   ph3: read ahi(8);        STG (tt+2).B1;                 bar; lgkm(0); MFMA ahi x bhi
//   ph4:                     STG (tt+2).A0; vmcnt(6);       bar;          MFMA ahi x blo
// No sched_barriers (m141: pinning regresses). WAR: every STG targets a region whose
// readers drained at a previous phase's lgkm(0) + closing barrier. RAW: ph4's vmcnt(6)
// leaves exactly the 3 youngest half-tiles (tile tt+2) in flight -> tile tt+1 staged.

__global__ __launch_bounds__(512, 2) void gemm_bt(const bf16* __restrict__ A,
                                                  const bf16* __restrict__ B,
                                                  const float* __restrict__ rowsq,
                                                  float* __restrict__ C,
                                                  float* __restrict__ colpart) {
  __shared__ __align__(16) bf16 sm[2][4][8192];
  __shared__ float lsc[2][256];
  char* smb = (char*)sm;

  const int t = threadIdx.x;
  const int i0 = blockIdx.y * 256;
  const int j0 = blockIdx.x * 256;
  const int w = t >> 6, l = t & 63;
  const int wr = w >> 2, wc = w & 3;      // wave grid 2 (M) x 4 (N)
  const int lr = l & 15, lq = l >> 4;

  // staging constants: 2 x 16B chunks per thread per half-tile (128x64 bf16 = 1024 chunks)
  const int c0 = t, c1 = t + 512;
  const int r0 = c0 >> 3, r1 = c1 >> 3;
  const int g0 = ((c0 & 7) ^ (r0 & 7)) * 8;   // pre-swizzled source column (bf16 units)
  const int g1 = ((c1 & 7) ^ (r1 & 7)) * 8;

  const bf16* A0p = A + (size_t)i0 * NN;            // A rows i0 +   0..127
  const bf16* A1p = A0p + (size_t)128 * NN;         // A rows i0 + 128..255
  const bf16* B0p = B + (size_t)j0 * NN;
  const bf16* B1p = B0p + (size_t)128 * NN;

  // ds_read constants (row & 7 == lr & 7 for all fragment rows)
  const int jx0 = lq ^ (lr & 7);
  const int jx1 = (4 + lq) ^ (lr & 7);
  const int aO0 = lr * 128 + jx0 * 16;
  const int aO1 = lr * 128 + jx1 * 16;
  const int brO = (wc & 1) * 8192;                  // 64-row offset within B half

  f32x4 acc[8][4] = {};

  auto STG = [&](const bf16* gp, char* ld) {
    gld16(gp + (size_t)r0 * NN + g0, ld + c0 * 16);
    gld16(gp + (size_t)r1 * NN + g1, ld + c1 * 16);
  };

  // ---- prologue: stage 0.B0 0.B1 0.A0 0.A1 1.B0 1.B1 1.A0 (7 half-tiles = 14 loads) ----
  {
    char* s0 = smb;
    char* s1 = smb + 65536;
    STG(B0p, s0 + 32768);
    STG(B1p, s0 + 49152);
    STG(A0p, s0);
    STG(A1p, s0 + 16384);
    STG(B0p + 64, s1 + 32768);
    STG(B1p + 64, s1 + 49152);
    STG(A0p + 64, s1);
  }
  asm volatile("s_waitcnt vmcnt(6)" ::: "memory");   // K-tile 0 fully staged
  __builtin_amdgcn_s_barrier();

  #pragma unroll 1
  for (int tt = 0; tt < KTILES; ++tt) {
    const int cur = tt & 1;
    char* baseC = smb + (cur << 16);
    char* baseN = smb + ((cur ^ 1) << 16);
    const char* Arw = baseC + wr * 16384;
    const char* Brw = baseC + 32768 + ((wc >> 1) << 14) + brO;

    bf16x8 bg[4][2], af[4][2];

    // ---- phase 1: read blo(4) + alo(8); stage (tt+1).A1; MFMA Alo x Blo ----
    #pragma unroll
    for (int jj = 0; jj < 2; ++jj) {
      bg[jj][0] = *(const bf16x8*)(Brw + jj * 2048 + aO0);
      bg[jj][1] = *(const bf16x8*)(Brw + jj * 2048 + aO1);
    }
    #pragma unroll
    for (int i = 0; i < 4; ++i) {
      af[i][0] = *(const bf16x8*)(Arw + i * 2048 + aO0);
      af[i][1] = *(const bf16x8*)(Arw + i * 2048 + aO1);
    }
    if (tt < KTILES - 1) STG(A1p + (tt + 1) * 64, baseN + 16384);
    asm volatile("s_waitcnt lgkmcnt(8)" ::: "memory");  // smooth: 4 oldest reads done pre-barrier
    __builtin_amdgcn_s_barrier();
    asm volatile("s_waitcnt lgkmcnt(0)" ::: "memory");
    __builtin_amdgcn_s_setprio(1);
    #pragma unroll
    for (int i = 0; i < 4; ++i)
      #pragma unroll
      for (int jj = 0; jj < 2; ++jj) {
        acc[i][jj] = MFMA16(af[i][0], bg[jj][0], acc[i][jj]);
        acc[i][jj] = MFMA16(af[i][1], bg[jj][1], acc[i][jj]);
      }
    __builtin_amdgcn_s_setprio(0);
    __builtin_amdgcn_s_barrier();

    // ---- phase 2: read bhi(4); stage (tt+2).B0 (blo readers drained ph1); MFMA Alo x Bhi ----
    #pragma unroll
    for (int jj = 2; jj < 4; ++jj) {
      bg[jj][0] = *(const bf16x8*)(Brw + jj * 2048 + aO0);
      bg[jj][1] = *(const bf16x8*)(Brw + jj * 2048 + aO1);
    }
    if (tt < KTILES - 2) STG(B0p + (tt + 2) * 64, baseC + 32768);
    __builtin_amdgcn_s_barrier();
    asm volatile("s_waitcnt lgkmcnt(0)" ::: "memory");
    __builtin_amdgcn_s_setprio(1);
    #pragma unroll
    for (int i = 0; i < 4; ++i)
      #pragma unroll
      for (int jj = 0; jj < 2; ++jj) {
        acc[i][2 + jj] = MFMA16(af[i][0], bg[2 + jj][0], acc[i][2 + jj]);
        acc[i][2 + jj] = MFMA16(af[i][1], bg[2 + jj][1], acc[i][2 + jj]);
      }
    __builtin_amdgcn_s_setprio(0);
    __builtin_amdgcn_s_barrier();

    // ---- phase 3: read ahi(8, reuse af); stage (tt+2).B1 (bhi readers drained ph2); MFMA Ahi x Bhi ----
    #pragma unroll
    for (int i = 0; i < 4; ++i) {
      af[i][0] = *(const bf16x8*)(Arw + 8192 + i * 2048 + aO0);
      af[i][1] = *(const bf16x8*)(Arw + 8192 + i * 2048 + aO1);
    }
    if (tt < KTILES - 2) STG(B1p + (tt + 2) * 64, baseC + 49152);
    __builtin_amdgcn_s_barrier();
    asm volatile("s_waitcnt lgkmcnt(0)" ::: "memory");
    __builtin_amdgcn_s_setprio(1);
    #pragma unroll
    for (int i = 0; i < 4; ++i)
      #pragma unroll
      for (int jj = 0; jj < 2; ++jj) {
        acc[4 + i][2 + jj] = MFMA16(af[i][0], bg[2 + jj][0], acc[4 + i][2 + jj]);
        acc[4 + i][2 + jj] = MFMA16(af[i][1], bg[2 + jj][1], acc[4 + i][2 + jj]);
      }
    __builtin_amdgcn_s_setprio(0);
    __builtin_amdgcn_s_barrier();

    // ---- phase 4: stage (tt+2).A0 (alo readers drained ph1); counted vmcnt; MFMA Ahi x Blo ----
    if (tt < KTILES - 2) {
      STG(A0p + (tt + 2) * 64, baseC);
      asm volatile("s_waitcnt vmcnt(6)" ::: "memory");   // tile tt+1 guaranteed staged
    } else if (tt == KTILES - 2) {
      asm volatile("s_waitcnt vmcnt(0)" ::: "memory");   // drain for the final K-tile
    }
    __builtin_amdgcn_s_barrier();
    __builtin_amdgcn_s_setprio(1);
    #pragma unroll
    for (int i = 0; i < 4; ++i)
      #pragma unroll
      for (int jj = 0; jj < 2; ++jj) {
        acc[4 + i][jj] = MFMA16(af[i][0], bg[jj][0], acc[4 + i][jj]);
        acc[4 + i][jj] = MFMA16(af[i][1], bg[jj][1], acc[4 + i][jj]);
      }
    __builtin_amdgcn_s_setprio(0);
    __builtin_amdgcn_s_barrier();
  }

  // ---- epilogue: C = x2 + y2 - 2*acc, fused colpart = sum_rows exp(-10*C) ----
  float y2v[4], ec[4] = {0.f, 0.f, 0.f, 0.f};
  #pragma unroll
  for (int jj = 0; jj < 4; ++jj) y2v[jj] = rowsq[NN + j0 + wc * 64 + 16 * jj + lr];
  #pragma unroll
  for (int m = 0; m < 8; ++m) {
    #pragma unroll
    for (int r = 0; r < 4; ++r) {
      int grow = i0 + wr * 128 + 16 * m + lq * 4 + r;
      float x2 = rowsq[grow];
      size_t rowoff = (size_t)grow * NN + j0 + wc * 64;
      #pragma unroll
      for (int jj = 0; jj < 4; ++jj) {
        float cv = x2 + y2v[jj] - 2.0f * acc[m][jj][r];
        C[rowoff + 16 * jj + lr] = cv;
        ec[jj] += expf(-10.0f * cv);
      }
    }
  }
  // reduce over lq (lanes lr, lr+16, lr+32, lr+48 hold the same columns)
  #pragma unroll
  for (int jj = 0; jj < 4; ++jj) {
    ec[jj] += __shfl_xor(ec[jj], 16, 64);
    ec[jj] += __shfl_xor(ec[jj], 32, 64);
  }
  if (lq == 0) {
    #pragma unroll
    for (int jj = 0; jj < 4; ++jj) lsc[wr][wc * 64 + 16 * jj + lr] = ec[jj];
  }
  __syncthreads();
  if (t < 256) colpart[(size_t)blockIdx.y * NN + j0 + t] = lsc[0][t] + lsc[1][t];
}

// ---------- kernel 3: s_j = log_nu - log(colsum) as fp32 ----------

__global__ void col_lse_final(const float* __restrict__ colpart, float* __restrict__ sdf) {
  int col = blockIdx.x * 256 + threadIdx.x;
  double s = 0.0;
  #pragma unroll
  for (int ch = 0; ch < 16; ++ch) s += (double)colpart[(size_t)ch * NN + col];
  double log_nu = log(1.0 / (double)NN + 1e-8);
  sdf[col] = (float)(log_nu - log(s));
}

// ---------- kernel 4: pi = exp(-10*C + s_j), fused cost partials (fp32 math) ----------

__global__ void pi_cost(const float* __restrict__ Cm, const float* __restrict__ sdf,
                        float* __restrict__ pi, double* __restrict__ costpart) {
  size_t idx0 = (size_t)blockIdx.x * 2048 + threadIdx.x;
  float facc = 0.0f;
  #pragma unroll
  for (int j = 0; j < 8; ++j) {
    size_t idx = idx0 + 256 * j;
    float c = Cm[idx];
    int col = (int)(idx & (NN - 1));
    float p = expf(fmaf(-10.0f, c, sdf[col]));
    pi[idx] = p;
    facc = fmaf(p, c, facc);
  }
  double total = blockSumD((double)facc);
  if (threadIdx.x == 0) costpart[blockIdx.x] = total;
}

// ---------- kernel 5: final cost reduction ----------

__global__ void cost_final(const double* __restrict__ costpart, float* __restrict__ out) {
  double s = 0.0;
  #pragma unroll
  for (int j = 0; j < 32; ++j) s += costpart[threadIdx.x + 256 * j];
  double total = blockSumD(s);
  if (threadIdx.x == 0) out[0] = (float)total;
}

// ---------- launch ----------

extern "C" void kernel_launch(void* const* d_in, const int* in_sizes, int n_in,
                              void* d_out, int out_size, void* d_ws, size_t ws_size,
                              hipStream_t stream) {
  const float* x = (const float*)d_in[0];
  const float* y = (const float*)d_in[1];
  float* out = (float*)d_out;
  float* pi = out + 1;                          // [NN*NN] floats
  float* Cm = out + 1 + (size_t)NN * NN;        // [NN*NN] floats

  char* ws = (char*)d_ws;
  bf16* xh = (bf16*)ws;                                          // 32 MiB
  bf16* yh = xh + (size_t)NN * NN;                               // 32 MiB
  size_t off = (size_t)NN * NN * 2 * 2;
  float* rowsq = (float*)(ws + off);       off += 2 * NN * 4;    // 32 KiB
  float* sdf = (float*)(ws + off);         off += NN * 4;        // 16 KiB
  float* colpart = (float*)(ws + off);     off += 32 * NN * 4;   // 512 KiB (16 rows used)
  double* costpart = (double*)(ws + off);  off += 8192 * 8;      // 64 KiB

  hipLaunchKernelGGL(softmax_rows, dim3(2 * NN), dim3(256), 0, stream, x, y, xh, yh, rowsq);
  hipLaunchKernelGGL(gemm_bt, dim3(16, 16), dim3(512), 0, stream, xh, yh, rowsq, Cm, colpart);
  hipLaunchKernelGGL(col_lse_final, dim3(16), dim3(256), 0, stream, colpart, sdf);
  hipLaunchKernelGGL(pi_cost, dim3(8192), dim3(256), 0, stream, Cm, sdf, pi, costpart);
  hipLaunchKernelGGL(cost_final, dim3(1), dim3(256), 0, stream, costpart, out);
}